// Round 1
// 1726.380 us; speedup vs baseline: 1.3533x; 1.3533x over previous
//
#include <hip/hip_runtime.h>

#define FLTMAX 3.402823466e+38f

// ---------- helpers ----------
__device__ inline float b2f(unsigned short u){
    return __uint_as_float(((unsigned int)u) << 16);
}
// flag-dispatched input load: mode=1 -> f32 buffer, mode=0 -> bf16 buffer
__device__ inline float ldin(const void* p, long i, int f32m){
    return f32m ? ((const float*)p)[i] : b2f(((const unsigned short*)p)[i]);
}
__device__ inline int pix_idx(float lx, float ly, float half_, int wh){
    lx = fminf(fmaxf(lx, -1.f), 1.f);
    ly = fminf(fmaxf(ly, -1.f), 1.f);
    int px = (int)rintf((lx + 1.f) * half_ - 0.5f);   // round-half-even = jnp.round
    int py = (int)rintf((ly + 1.f) * half_ - 0.5f);
    px = min(max(px, 0), wh - 1);
    py = min(max(py, 0), wh - 1);
    return py * wh + px;
}
__device__ inline void ins5(float* b5, float d){
    if(d < b5[4]){
        b5[4] = d;
#pragma unroll
        for(int q = 4; q > 0; --q){
            if(b5[q] < b5[q-1]){ float tm = b5[q]; b5[q] = b5[q-1]; b5[q-1] = tm; }
        }
    }
}
__device__ inline float wred_add(float v){
    for(int o = 32; o > 0; o >>= 1) v += __shfl_down(v, o);
    return v;
}

// ---------- dtype auto-detect (64 blocks, atomic count; mode[0] = hit count) ----------
__global__ __launch_bounds__(256) void detect_mode(const void* xraw, int* flag){
    __shared__ int sh[256];
    const unsigned short* p = (const unsigned short*)xraw;
    int t = threadIdx.x, c = 0;
    int base = blockIdx.x * 1024;
    for(int i = base + t; i < base + 1024; i += 256){
        float v = b2f(p[i]);
        if(!(fabsf(v) < 100.f)) c++;
    }
    sh[t] = c;
    __syncthreads();
    for(int s = 128; s > 0; s >>= 1){
        if(t < s) sh[t] += sh[t + s];
        __syncthreads();
    }
    if(t == 0 && sh[0] > 0) atomicAdd(flag, sh[0]);
}
#define GETM(modeptr) (((*(modeptr)) > 64) ? 1 : 0)

// ---------- small utility kernels ----------
__global__ void fill_f32(float* p, float v, int n){
    int i = blockIdx.x * blockDim.x + threadIdx.x;
    if(i < n) p[i] = v;
}

// token2map scatter
__global__ __launch_bounds__(256) void scatter_map(const void* x, const void* loc,
                                                   const int* idx_agg, float* acc, float* cnt,
                                                   const int* mode){
    int m = GETM(mode);
    int bn = blockIdx.x;                 // 0..16383
    int b = bn >> 12;
    float lx = ldin(loc, (long)bn * 2 + 0, m);
    float ly = ldin(loc, (long)bn * 2 + 1, m);
    int p = pix_idx(lx, ly, 32.f, 64);
    int ia = idx_agg[bn] & 4095;
    long src = ((long)(b << 12) + ia) * 256;
    float* dst = acc + ((size_t)(b << 12) + p) * 256;
    int t = threadIdx.x;                 // 256 = C
    unsafeAtomicAdd(&dst[t], ldin(x, src + t, m));
    if(t == 0) unsafeAtomicAdd(&cnt[(b << 12) + p], 1.0f);
}

__global__ void divide_map(float* xmap, const float* cnt, int n){
    int i = blockIdx.x * 256 + threadIdx.x;
    if(i < n) xmap[i] = xmap[i] / (cnt[i >> 8] + 1e-6f);
}

// ---------- GEMM: skip  (x[16384,256] @ skip_w[256,512] -> xtok f32) ----------
__global__ __launch_bounds__(256) void gemm_skip(const void* A, const void* Bw, float* C,
                                                 const int* mode){
    int m = GETM(mode);
    __shared__ float As[16][68];
    __shared__ float Bs[16][68];
    int i0 = blockIdx.y * 64, j0 = blockIdx.x * 64;
    int t = threadIdx.x, tx = t & 15, ty = t >> 4;
    float acc[4][4] = {};
    for(int k0 = 0; k0 < 256; k0 += 16){
        int ia = t >> 2, kc = (t & 3) << 2;
#pragma unroll
        for(int u = 0; u < 4; ++u)
            As[kc+u][ia] = ldin(A, (long)(i0 + ia) * 256 + k0 + kc + u, m);
        int kb = t >> 4, jb = (t & 15) << 2;
        float4 bv;
        bv.x = ldin(Bw, (long)(k0 + kb) * 512 + j0 + jb + 0, m);
        bv.y = ldin(Bw, (long)(k0 + kb) * 512 + j0 + jb + 1, m);
        bv.z = ldin(Bw, (long)(k0 + kb) * 512 + j0 + jb + 2, m);
        bv.w = ldin(Bw, (long)(k0 + kb) * 512 + j0 + jb + 3, m);
        *(float4*)&Bs[kb][jb] = bv;
        __syncthreads();
#pragma unroll
        for(int kk = 0; kk < 16; ++kk){
            float4 a4 = *(const float4*)&As[kk][ty << 2];
            float4 b4 = *(const float4*)&Bs[kk][tx << 2];
            float ar[4] = {a4.x, a4.y, a4.z, a4.w};
            float br[4] = {b4.x, b4.y, b4.z, b4.w};
#pragma unroll
            for(int di = 0; di < 4; ++di)
#pragma unroll
                for(int dj = 0; dj < 4; ++dj)
                    acc[di][dj] = fmaf(ar[di], br[dj], acc[di][dj]);
        }
        __syncthreads();
    }
#pragma unroll
    for(int di = 0; di < 4; ++di){
        size_t i = i0 + (ty << 2) + di;
#pragma unroll
        for(int dj = 0; dj < 4; ++dj)
            C[i * 512 + j0 + (tx << 2) + dj] = acc[di][dj];
    }
}

// ---------- conv C init with bias ----------
__global__ void init_convo(float* convo, const void* bias, const int* mode){
    int m = GETM(mode);
    int e = blockIdx.x * 256 + threadIdx.x;   // 2,097,152
    convo[e] = ldin(bias, e & 511, m);
}

// ---------- conv3x3 s2 p1 via im2col: 128x128 tile, K-split x4, prefetch, atomic epilogue ----------
__global__ __launch_bounds__(256) void gemm_conv(const float* xmap, const void* Bw,
                                                 float* C, const int* mode){
    int m = GETM(mode);
    __shared__ float As[16][132];
    __shared__ float Bs[16][132];
    int i0 = blockIdx.y * 128, j0 = blockIdx.x * 128;
    int kz = blockIdx.z;                       // 0..3, K chunk of 576
    int t = threadIdx.x, tx = t & 15, ty = t >> 4;
    int ia = t >> 1, kc = (t & 1) << 3;        // it-invariant
    int p = i0 + ia;
    int b = p >> 10, r = p & 1023, oy = r >> 5, ox = r & 31;
    int kb = t >> 4, jb = (t & 15) << 3;
    float acc[8][8] = {};
    float4 v0, v1, w0, w1;
    // load it=0
    {
        int k0 = kz * 576;
        int f = k0 >> 8; int ky = f / 3, kx = f % 3; int c0 = k0 & 255;
        int iy = 2 * oy - 1 + ky, ix = 2 * ox - 1 + kx;
        v0 = make_float4(0.f,0.f,0.f,0.f); v1 = v0;
        if(iy >= 0 && iy < 64 && ix >= 0 && ix < 64){
            const float* src = &xmap[((size_t)(b << 12) + (iy << 6) + ix) * 256 + c0 + kc];
            v0 = *(const float4*)src; v1 = *(const float4*)(src + 4);
        }
        long bo = (long)(k0 + kb) * 512 + j0 + jb;
        w0.x = ldin(Bw, bo+0, m); w0.y = ldin(Bw, bo+1, m);
        w0.z = ldin(Bw, bo+2, m); w0.w = ldin(Bw, bo+3, m);
        w1.x = ldin(Bw, bo+4, m); w1.y = ldin(Bw, bo+5, m);
        w1.z = ldin(Bw, bo+6, m); w1.w = ldin(Bw, bo+7, m);
    }
    for(int it = 0; it < 36; ++it){
        As[kc+0][ia] = v0.x; As[kc+1][ia] = v0.y; As[kc+2][ia] = v0.z; As[kc+3][ia] = v0.w;
        As[kc+4][ia] = v1.x; As[kc+5][ia] = v1.y; As[kc+6][ia] = v1.z; As[kc+7][ia] = v1.w;
        *(float4*)&Bs[kb][jb] = w0;
        *(float4*)&Bs[kb][jb+4] = w1;
        if(it + 1 < 36){                      // prefetch it+1 before the barrier
            int k0 = kz * 576 + (it + 1) * 16;
            int f = k0 >> 8; int ky = f / 3, kx = f % 3; int c0 = k0 & 255;
            int iy = 2 * oy - 1 + ky, ix = 2 * ox - 1 + kx;
            v0 = make_float4(0.f,0.f,0.f,0.f); v1 = v0;
            if(iy >= 0 && iy < 64 && ix >= 0 && ix < 64){
                const float* src = &xmap[((size_t)(b << 12) + (iy << 6) + ix) * 256 + c0 + kc];
                v0 = *(const float4*)src; v1 = *(const float4*)(src + 4);
            }
            long bo = (long)(k0 + kb) * 512 + j0 + jb;
            w0.x = ldin(Bw, bo+0, m); w0.y = ldin(Bw, bo+1, m);
            w0.z = ldin(Bw, bo+2, m); w0.w = ldin(Bw, bo+3, m);
            w1.x = ldin(Bw, bo+4, m); w1.y = ldin(Bw, bo+5, m);
            w1.z = ldin(Bw, bo+6, m); w1.w = ldin(Bw, bo+7, m);
        }
        __syncthreads();
#pragma unroll
        for(int kk = 0; kk < 16; ++kk){
            float4 a0r = *(const float4*)&As[kk][ty << 3];
            float4 a1r = *(const float4*)&As[kk][(ty << 3) + 4];
            float4 b0r = *(const float4*)&Bs[kk][tx << 2];
            float4 b1r = *(const float4*)&Bs[kk][64 + (tx << 2)];
            float ar[8] = {a0r.x, a0r.y, a0r.z, a0r.w, a1r.x, a1r.y, a1r.z, a1r.w};
            float br[8] = {b0r.x, b0r.y, b0r.z, b0r.w, b1r.x, b1r.y, b1r.z, b1r.w};
#pragma unroll
            for(int di = 0; di < 8; ++di)
#pragma unroll
                for(int dj = 0; dj < 8; ++dj)
                    acc[di][dj] = fmaf(ar[di], br[dj], acc[di][dj]);
        }
        __syncthreads();
    }
#pragma unroll
    for(int di = 0; di < 8; ++di){
        size_t i = i0 + (ty << 3) + di;
#pragma unroll
        for(int u = 0; u < 4; ++u){
            unsafeAtomicAdd(&C[i * 512 + j0 + (tx << 2) + u], acc[di][u]);
            unsafeAtomicAdd(&C[i * 512 + j0 + 64 + (tx << 2) + u], acc[di][4 + u]);
        }
    }
}

// ---------- map2token ----------
__global__ void wsum_add(const int* idx_agg, const void* aggw, float* wsum, const int* mode){
    int m = GETM(mode);
    int e = blockIdx.x * 256 + threadIdx.x;   // 16384
    int b = e >> 12;
    unsafeAtomicAdd(&wsum[(b << 12) + (idx_agg[e] & 4095)], ldin(aggw, e, m));
}

__global__ __launch_bounds__(128) void scatter_tok(const void* loc, const int* idx_agg,
                                                   const void* aggw, const float* convo,
                                                   const float* wsum, float* xtok, const int* mode){
    int m = GETM(mode);
    int bn = blockIdx.x;
    int b = bn >> 12;
    float lx = ldin(loc, (long)bn * 2 + 0, m);
    float ly = ldin(loc, (long)bn * 2 + 1, m);
    int p = pix_idx(lx, ly, 16.f, 32);
    int tk = idx_agg[bn] & 4095;
    float w = ldin(aggw, bn, m);
    float scale = w / wsum[(b << 12) + tk];
    const float* pv = convo + ((size_t)(b << 10) + p) * 512;
    float* dst = xtok + ((size_t)(b << 12) + tk) * 512;
    int c = threadIdx.x * 4;
    float4 v = *(const float4*)&pv[c];
    unsafeAtomicAdd(&dst[c + 0], v.x * scale);
    unsafeAtomicAdd(&dst[c + 1], v.y * scale);
    unsafeAtomicAdd(&dst[c + 2], v.z * scale);
    unsafeAtomicAdd(&dst[c + 3], v.w * scale);
}

// ---------- fused layernorm + conf + weight + x2 ----------
__global__ __launch_bounds__(128) void ln_conf(float* xtok, const void* g_, const void* b_,
                                               const void* cw_, const void* cb_,
                                               float* wgt, float* x2a, const int* mode){
    int m = GETM(mode);
    int row = blockIdx.x;        // 0..16383
    int t = threadIdx.x;         // 128
    float* xr = xtok + (size_t)row * 512;
    int c0 = t * 4;
    float4 v = *(const float4*)&xr[c0];
    float xv[4] = {v.x, v.y, v.z, v.w};
    __shared__ float red[2];
    __shared__ float red2[4];
    float s = xv[0] + xv[1] + xv[2] + xv[3];
    s = wred_add(s);
    if((t & 63) == 0) red[t >> 6] = s;
    __syncthreads();
    float mean = (red[0] + red[1]) * (1.f / 512.f);
    __syncthreads();
    float xc[4];
#pragma unroll
    for(int u = 0; u < 4; ++u) xc[u] = xv[u] - mean;
    float q = xc[0]*xc[0] + xc[1]*xc[1] + xc[2]*xc[2] + xc[3]*xc[3];
    q = wred_add(q);
    if((t & 63) == 0) red[t >> 6] = q;
    __syncthreads();
    float var = (red[0] + red[1]) * (1.f / 512.f);
    float rs = 1.0f / sqrtf(var + 1e-5f);
    float y[4];
#pragma unroll
    for(int u = 0; u < 4; ++u)
        y[u] = xc[u] * rs * ldin(g_, c0 + u, m) + ldin(b_, c0 + u, m);
    float4 st; st.x = y[0]; st.y = y[1]; st.z = y[2]; st.w = y[3];
    *(float4*)&xr[c0] = st;
    float cf = y[0]*ldin(cw_, c0+0, m) + y[1]*ldin(cw_, c0+1, m)
             + y[2]*ldin(cw_, c0+2, m) + y[3]*ldin(cw_, c0+3, m);
    float qq = y[0]*y[0] + y[1]*y[1] + y[2]*y[2] + y[3]*y[3];
    cf = wred_add(cf);
    qq = wred_add(qq);
    if((t & 63) == 0){ red2[t >> 6] = cf; red2[2 + (t >> 6)] = qq; }
    __syncthreads();
    if(t == 0){
        wgt[row] = expf(red2[0] + red2[1] + ldin(cb_, 0, m));
        x2a[row] = red2[2] + red2[3];
    }
}

// ================== MFMA Gram path (fp16 2-way split, 3-product exact emulation) ==================
//
// x = h + l exactly to 2^-23 rel (h = f16(x), l = f16(x-h), both subtractions Sterbenz-exact).
// dot(x,y) = hh + hl + lh accumulated in fp32 by v_mfma_f32_32x32x16_f16; dropped ll ~ 2^-24 rel
// => fp32-parity d2. Split arrays SP are stored k-group-transposed: SP[s][g][16384][8] f16 bits,
// so global_load_lds(16B) staging is fully coalesced AND the LDS tile [s][tile][g][128][8] gives
// perfectly contiguous (conflict-free) ds_read_b128 MFMA fragment loads.

typedef _Float16 half8 __attribute__((ext_vector_type(8)));
typedef float f32x16 __attribute__((ext_vector_type(16)));
#define MFMA16(A,B,C) __builtin_amdgcn_mfma_f32_32x32x16_f16(A,B,C,0,0,0)

__device__ inline void gld16(const unsigned short* g, unsigned short* l){
    __builtin_amdgcn_global_load_lds((const __attribute__((address_space(1))) unsigned int*)g,
                                     (__attribute__((address_space(3))) unsigned int*)l, 16, 0, 0);
}

// split kernel: xtok f32 [16384][512] -> SP[2][64][16384][8] fp16 bits
__global__ __launch_bounds__(256) void split2(const float* xt, unsigned short* SP){
    int e = blockIdx.x * 256 + threadIdx.x;   // 1,048,576 = 64 groups * 16384 rows
    int g = e >> 14, row = e & 16383;
    const float* src = xt + (size_t)row * 512 + g * 8;
    float4 a = *(const float4*)src;
    float4 b = *(const float4*)(src + 4);
    float v[8] = {a.x, a.y, a.z, a.w, b.x, b.y, b.z, b.w};
    unsigned hw[4], lw[4];
#pragma unroll
    for(int u = 0; u < 4; ++u){
        _Float16 h0 = (_Float16)v[2*u];
        _Float16 l0 = (_Float16)(v[2*u] - (float)h0);
        _Float16 h1 = (_Float16)v[2*u+1];
        _Float16 l1 = (_Float16)(v[2*u+1] - (float)h1);
        unsigned uh0 = __builtin_bit_cast(unsigned short, h0);
        unsigned ul0 = __builtin_bit_cast(unsigned short, l0);
        unsigned uh1 = __builtin_bit_cast(unsigned short, h1);
        unsigned ul1 = __builtin_bit_cast(unsigned short, l1);
        hw[u] = (uh1 << 16) | uh0;
        lw[u] = (ul1 << 16) | ul0;
    }
    *(uint4*)(void*)(SP + ((size_t)g * 16384 + row) * 8) = make_uint4(hw[0], hw[1], hw[2], hw[3]);
    *(uint4*)(void*)(SP + ((size_t)(64 + g) * 16384 + row) * 8) = make_uint4(lw[0], lw[1], lw[2], lw[3]);
}

// per-thread staging pointer init; cell = [s][tile][gl][row], 2048 cells of 16B per K-chunk(32)
#define INITP(R, AEXPR) const unsigned short* p##R; { \
    int cell = t + ((R) << 8); int row = cell & 127; int gl = (cell >> 7) & 3; \
    int tile = (cell >> 9) & 1; int sp_ = cell >> 10; \
    int grow = (z << 12) + (tile ? (j0 + row) : (AEXPR)); \
    p##R = SP + (size_t)((sp_ << 6) + gl) * 131072 + (size_t)grow * 8; }

// 128x128 Gram tile over K=512: acc{00,01,10,11} = f32x16 per wave-quadrant (2x2 of 32x32)
#define GRAM_CORE(AEXPR) \
    int w = t >> 6; int lane = t & 63; int kh = lane >> 5; \
    f32x16 acc00, acc01, acc10, acc11; \
    _Pragma("unroll") for(int q_ = 0; q_ < 16; ++q_){ acc00[q_]=0.f; acc01[q_]=0.f; acc10[q_]=0.f; acc11[q_]=0.f; } \
    INITP(0, AEXPR) INITP(1, AEXPR) INITP(2, AEXPR) INITP(3, AEXPR) \
    INITP(4, AEXPR) INITP(5, AEXPR) INITP(6, AEXPR) INITP(7, AEXPR) \
    { \
        unsigned short* ldsb = stage + (size_t)(t & 192) * 8; \
        int rb = ((w >> 1) << 6) + (lane & 31); \
        int cbx = ((w & 1) << 6) + (lane & 31); \
        for(int c_ = 0; c_ < 16; ++c_){ \
            __syncthreads(); \
            gld16(p0, ldsb);         gld16(p1, ldsb + 2048); \
            gld16(p2, ldsb + 4096);  gld16(p3, ldsb + 6144); \
            gld16(p4, ldsb + 8192);  gld16(p5, ldsb + 10240); \
            gld16(p6, ldsb + 12288); gld16(p7, ldsb + 14336); \
            p0 += 524288; p1 += 524288; p2 += 524288; p3 += 524288; \
            p4 += 524288; p5 += 524288; p6 += 524288; p7 += 524288; \
            __syncthreads(); \
            const half8* stv = (const half8*)stage; \
            _Pragma("unroll") \
            for(int ks = 0; ks < 2; ++ks){ \
                int kg = (ks << 1) + kh; \
                half8 ah0 = stv[kg*128 + rb];        half8 ah1 = stv[kg*128 + rb + 32]; \
                half8 bh0 = stv[(4+kg)*128 + cbx];   half8 bh1 = stv[(4+kg)*128 + cbx + 32]; \
                half8 al0 = stv[(8+kg)*128 + rb];    half8 al1 = stv[(8+kg)*128 + rb + 32]; \
                half8 bl0 = stv[(12+kg)*128 + cbx];  half8 bl1 = stv[(12+kg)*128 + cbx + 32]; \
                acc00 = MFMA16(ah0,bh0,acc00); acc00 = MFMA16(ah0,bl0,acc00); acc00 = MFMA16(al0,bh0,acc00); \
                acc01 = MFMA16(ah0,bh1,acc01); acc01 = MFMA16(ah0,bl1,acc01); acc01 = MFMA16(al0,bh1,acc01); \
                acc10 = MFMA16(ah1,bh0,acc10); acc10 = MFMA16(ah1,bl0,acc10); acc10 = MFMA16(al1,bh0,acc10); \
                acc11 = MFMA16(ah1,bh1,acc11); acc11 = MFMA16(ah1,bl1,acc11); acc11 = MFMA16(al1,bh1,acc11); \
            } \
        } \
    }

// dump one 32x32 acc quadrant as d2 into the LDS half-tile (rows of wave's half, 64x128 f32)
// C/D layout (m74/m101-verified): col = lane&31, row = (q&3) + 8*(q>>2) + 4*(lane>>5)
#define DUMP_ONE(ACC, M, N) { \
    int coln = ((w & 1) << 6) + ((N) << 5) + (lane & 31); \
    float xc2v = x2c[coln]; \
    _Pragma("unroll") for(int q = 0; q < 16; ++q){ \
        int rL = ((M) << 5) + (q & 3) + ((q >> 2) << 3) + (kh << 2); \
        d2t[rL * 128 + coln] = x2r[(ph << 6) + rL] + xc2v - 2.0f * ACC[q]; } }

#define DUMP4 if((w >> 1) == ph){ DUMP_ONE(acc00,0,0) DUMP_ONE(acc01,0,1) DUMP_ONE(acc10,1,0) DUMP_ONE(acc11,1,1) }

// triangular block map: q -> (bi <= bj)
#define TRI_MAP(q, bi, bj)                                         \
    int bj = (int)((sqrtf(8.0f * (q) + 1.0f) - 1.0f) * 0.5f);      \
    while((bj + 1) * (bj + 2) / 2 <= (q)) bj++;                    \
    while(bj * (bj + 1) / 2 > (q)) bj--;                           \
    int bi = (q) - bj * (bj + 1) / 2;

// ---------- Pass A: top5 + max per row/col ----------
__global__ __launch_bounds__(256, 3) void gramA3(const unsigned short* SP, const float* x2b,
                                                 float* part5, float* pmax){
    __shared__ __align__(16) unsigned short stage[16384];   // 32KB staging, aliased as d2 tile
    __shared__ float x2r[128], x2c[128];
    __shared__ float scr[1536];
    float* d2t = (float*)stage;
    int z = blockIdx.z;
    TRI_MAP((int)blockIdx.x, bi, bj)
    int i0 = bi * 128, j0 = bj * 128;
    int t = threadIdx.x;
    if(t < 128) x2r[t] = x2b[(z << 12) + i0 + t];
    else        x2c[t - 128] = x2b[(z << 12) + j0 + (t - 128)];
    GRAM_CORE(i0 + row)
    float colb5[5] = {FLTMAX, FLTMAX, FLTMAX, FLTMAX, FLTMAX};
    float colmx = -FLTMAX;
    for(int ph = 0; ph < 2; ++ph){
        __syncthreads();
        DUMP4
        __syncthreads();
        {   // row scan: 4 threads/row, 32 cols each, staggered to avoid bank conflicts
            int rr = t >> 2, ch = t & 3;
            float b5[5] = {FLTMAX, FLTMAX, FLTMAX, FLTMAX, FLTMAX};
            float mx = -FLTMAX;
#pragma unroll
            for(int c = 0; c < 32; ++c){
                int cc = (rr + (ch << 3) + c) & 31;
                float v = d2t[rr * 128 + (ch << 5) + cc];
                ins5(b5, v); mx = fmaxf(mx, v);
            }
            float* sp_ = &scr[(size_t)(rr * 4 + ch) * 6];
            sp_[0]=b5[0]; sp_[1]=b5[1]; sp_[2]=b5[2]; sp_[3]=b5[3]; sp_[4]=b5[4]; sp_[5]=mx;
        }
        __syncthreads();
        if(t < 64){
            float m5[5] = {FLTMAX, FLTMAX, FLTMAX, FLTMAX, FLTMAX};
            float mmx = -FLTMAX;
            for(int c2 = 0; c2 < 4; ++c2){
                const float* sp_ = &scr[(size_t)(t * 4 + c2) * 6];
                ins5(m5, sp_[0]); ins5(m5, sp_[1]); ins5(m5, sp_[2]); ins5(m5, sp_[3]); ins5(m5, sp_[4]);
                mmx = fmaxf(mmx, sp_[5]);
            }
            size_t rowg = (size_t)(z << 12) + i0 + (ph << 6) + t;
            size_t o = (rowg * 32 + bj) * 5;
            part5[o]=m5[0]; part5[o+1]=m5[1]; part5[o+2]=m5[2]; part5[o+3]=m5[3]; part5[o+4]=m5[4];
            pmax[rowg * 32 + bj] = mmx;
        }
        __syncthreads();
        if(bi != bj){   // col partials (2 threads/col, 32 rows each)
            int col = t >> 1, rh = t & 1;
            float c5[5] = {FLTMAX, FLTMAX, FLTMAX, FLTMAX, FLTMAX};
            float cmx = -FLTMAX;
#pragma unroll
            for(int r2 = 0; r2 < 32; ++r2){
                float v = d2t[((rh << 5) + r2) * 128 + col];
                ins5(c5, v); cmx = fmaxf(cmx, v);
            }
            float* sp_ = &scr[(size_t)(col * 2 + rh) * 6];
            sp_[0]=c5[0]; sp_[1]=c5[1]; sp_[2]=c5[2]; sp_[3]=c5[3]; sp_[4]=c5[4]; sp_[5]=cmx;
        }
        __syncthreads();
        if(bi != bj && t < 128){
            const float* sa = &scr[(size_t)(t * 2) * 6];
            ins5(colb5, sa[0]); ins5(colb5, sa[1]); ins5(colb5, sa[2]); ins5(colb5, sa[3]); ins5(colb5, sa[4]);
            colmx = fmaxf(colmx, sa[5]);
            const float* sb = &scr[(size_t)(t * 2 + 1) * 6];
            ins5(colb5, sb[0]); ins5(colb5, sb[1]); ins5(colb5, sb[2]); ins5(colb5, sb[3]); ins5(colb5, sb[4]);
            colmx = fmaxf(colmx, sb[5]);
        }
    }
    if(bi != bj && t < 128){
        size_t rowg = (size_t)(z << 12) + j0 + t;
        size_t o = (rowg * 32 + bi) * 5;
        part5[o]=colb5[0]; part5[o+1]=colb5[1]; part5[o+2]=colb5[2]; part5[o+3]=colb5[3]; part5[o+4]=colb5[4];
        pmax[rowg * 32 + bi] = colmx;
    }
}

__global__ __launch_bounds__(64) void reduceA2(const float* part5, const float* pmax,
                                               float* dens_b, int* dmax_b){
    int bi = blockIdx.x, t = threadIdx.x;     // bi = z*4096 + i, 0..16383
    __shared__ float l5[32][5];
    __shared__ float lm[32];
    if(t < 32){
#pragma unroll
        for(int q = 0; q < 5; ++q) l5[t][q] = part5[((size_t)bi * 32 + t) * 5 + q];
        lm[t] = pmax[(size_t)bi * 32 + t];
    }
    __syncthreads();
    if(t == 0){
        float m5[5] = {FLTMAX, FLTMAX, FLTMAX, FLTMAX, FLTMAX};
        float mm = -FLTMAX;
        for(int c = 0; c < 32; ++c){
            mm = fmaxf(mm, lm[c]);
#pragma unroll
            for(int q = 0; q < 5; ++q) ins5(m5, l5[c][q]);
        }
        const float sqrtC = 22.627416997969522f;
        float s = 0.f;
#pragma unroll
        for(int q = 0; q < 5; ++q){
            float d = sqrtf(fmaxf(m5[q], 0.f)) / sqrtC;
            s = s + d * d;
        }
        dens_b[bi] = expf(-(s / 5.0f));
        atomicMax(dmax_b + (bi >> 12), __float_as_int(fmaxf(mm, 0.f)));
    }
}

// ---------- Pass B: min dist to any higher-density token ----------
__global__ __launch_bounds__(256, 3) void gramB3(const unsigned short* SP, const float* x2b,
                                                 const float* dens_b, float* pmin){
    __shared__ __align__(16) unsigned short stage[16384];
    __shared__ float x2r[128], x2c[128], densr[128], densc[128];
    __shared__ float scr[256];
    float* d2t = (float*)stage;
    int z = blockIdx.z;
    TRI_MAP((int)blockIdx.x, bi, bj)
    int i0 = bi * 128, j0 = bj * 128;
    int t = threadIdx.x;
    if(t < 128){ x2r[t] = x2b[(z << 12) + i0 + t]; densr[t] = dens_b[(z << 12) + i0 + t]; }
    else { x2c[t-128] = x2b[(z << 12) + j0 + (t-128)]; densc[t-128] = dens_b[(z << 12) + j0 + (t-128)]; }
    GRAM_CORE(i0 + row)
    float colmin = FLTMAX;
    for(int ph = 0; ph < 2; ++ph){
        __syncthreads();
        DUMP4
        __syncthreads();
        {
            int rr = t >> 2, ch = t & 3;
            float dr = densr[(ph << 6) + rr];
            float pm = FLTMAX;
#pragma unroll
            for(int c = 0; c < 32; ++c){
                int cc = (rr + (ch << 3) + c) & 31;
                int coln = (ch << 5) + cc;
                float v = d2t[rr * 128 + coln];
                if(densc[coln] > dr) pm = fminf(pm, v);
            }
            scr[rr * 4 + ch] = pm;
        }
        __syncthreads();
        if(t < 64){
            float pm = fminf(fminf(scr[t*4], scr[t*4+1]), fminf(scr[t*4+2], scr[t*4+3]));
            pmin[((size_t)(z << 12) + i0 + (ph << 6) + t) * 32 + bj] = pm;
        }
        __syncthreads();
        if(bi != bj){
            int col = t >> 1, rh = t & 1;
            float dc = densc[col];
            float pm = FLTMAX;
#pragma unroll
            for(int r2 = 0; r2 < 32; ++r2){
                int rL = (rh << 5) + r2;
                float v = d2t[rL * 128 + col];
                if(densr[(ph << 6) + rL] > dc) pm = fminf(pm, v);
            }
            scr[col * 2 + rh] = pm;
        }
        __syncthreads();
        if(bi != bj && t < 128) colmin = fminf(colmin, fminf(scr[t*2], scr[t*2+1]));
    }
    if(bi != bj && t < 128) pmin[((size_t)(z << 12) + j0 + t) * 32 + bi] = colmin;
}

__global__ __launch_bounds__(64) void reduceB2(const float* pmin, const float* dens_b,
                                               const int* dmax_b, float* score_b){
    int bi = blockIdx.x, t = threadIdx.x;     // 0..16383
    __shared__ float lm[32];
    if(t < 32) lm[t] = pmin[(size_t)bi * 32 + t];
    __syncthreads();
    if(t == 0){
        float m = FLTMAX;
        for(int c = 0; c < 32; ++c) m = fminf(m, lm[c]);
        const float sqrtC = 22.627416997969522f;
        float dp;
        if(m == FLTMAX) dp = sqrtf(fmaxf(__int_as_float(dmax_b[bi >> 12]), 0.f)) / sqrtC;
        else            dp = sqrtf(fmaxf(m, 0.f)) / sqrtC;
        score_b[bi] = dp * dens_b[bi];
    }
}

// ---------- Pass C: gathered-center Gram -> per-(token, centerblock) argmin ----------
__global__ __launch_bounds__(256, 3) void gramC3(const unsigned short* SP, const float* x2b,
                                                 const int* idown_b, float* pcd, int* pci){
    __shared__ __align__(16) unsigned short stage[16384];
    __shared__ float x2r[128], x2c[128];
    __shared__ int idzl[128];
    __shared__ float scrD[256];
    __shared__ int scrI[256];
    float* d2t = (float*)stage;
    int z = blockIdx.z;
    int s0 = blockIdx.y * 128, j0 = blockIdx.x * 128;
    int t = threadIdx.x;
    if(t < 128) idzl[t] = idown_b[(z << 10) + s0 + t];
    else        x2c[t - 128] = x2b[(z << 12) + j0 + (t - 128)];
    __syncthreads();
    if(t < 128) x2r[t] = x2b[(z << 12) + idzl[t]];
    GRAM_CORE(idzl[row])
    const float sqrtC = 22.627416997969522f;
    float bd = FLTMAX; int bs = 0;
    for(int ph = 0; ph < 2; ++ph){
        __syncthreads();
        DUMP4
        __syncthreads();
        {
            int col = t >> 1, rh = t & 1;
            float ld = FLTMAX; int li = 0;
#pragma unroll
            for(int r2 = 0; r2 < 32; ++r2){      // ascending row => first-min ties stay first
                int rL = (rh << 5) + r2;
                float d2v = d2t[rL * 128 + col];
                float d = sqrtf(fmaxf(d2v, 0.f)) / sqrtC;
                if(d < ld){ ld = d; li = (ph << 6) + rL; }
            }
            scrD[col * 2 + rh] = ld; scrI[col * 2 + rh] = li;
        }
        __syncthreads();
        if(t < 128){
            if(scrD[t*2]   < bd){ bd = scrD[t*2];   bs = scrI[t*2]; }
            if(scrD[t*2+1] < bd){ bd = scrD[t*2+1]; bs = scrI[t*2+1]; }
        }
    }
    if(t < 128){
        pcd[((size_t)(z << 12) + j0 + t) * 8 + blockIdx.y] = bd;
        pci[((size_t)(z << 12) + j0 + t) * 8 + blockIdx.y] = s0 + bs;
    }
}

__global__ void reduceC2(const float* pcd, const int* pci, int* iclus_b){
    int jg = blockIdx.x * 256 + threadIdx.x;      // 0..16383
    float bd = FLTMAX;
    int bs = 0;
    for(int c = 0; c < 8; ++c){
        float d = pcd[(size_t)jg * 8 + c];
        if(d < bd){ bd = d; bs = pci[(size_t)jg * 8 + c]; }
    }
    iclus_b[jg] = bs;
}

// ---------- bitonic sort (score desc, idx asc) -> top 1024; blockIdx.x = batch ----------
__global__ __launch_bounds__(1024) void sort_topk(const float* score, int* idown){
    __shared__ float ss[4096];
    __shared__ int sid[4096];
    int t = threadIdx.x;
    const float* sc = score + (size_t)blockIdx.x * 4096;
    int* id = idown + (size_t)blockIdx.x * 1024;
    for(int v = t; v < 4096; v += 1024){ ss[v] = sc[v]; sid[v] = v; }
    __syncthreads();
    for(int k = 2; k <= 4096; k <<= 1){
        for(int j = k >> 1; j > 0; j >>= 1){
            for(int v = t; v < 4096; v += 1024){
                int l = v ^ j;
                if(l > v){
                    float sv = ss[v], sl = ss[l];
                    int iv = sid[v], il = sid[l];
                    bool before_lv = (sl > sv) || (sl == sv && il < iv);
                    bool before_vl = (sv > sl) || (sv == sl && iv < il);
                    bool asc = ((v & k) == 0);
                    bool sw = asc ? before_lv : before_vl;
                    if(sw){ ss[v] = sl; ss[l] = sv; sid[v] = il; sid[l] = iv; }
                }
            }
            __syncthreads();
        }
    }
    for(int v = t; v < 1024; v += 1024) id[v] = sid[v];
}

// ---------- merge tokens + outputs (FLOAT32 out) ----------
__global__ void allw_add(const int* iclus, const float* wgt, float* allw){
    int e = blockIdx.x * 256 + threadIdx.x;   // 16384
    int b = e >> 12;
    unsafeAtomicAdd(&allw[(b << 10) + (iclus[e] & 1023)], wgt[e]);
}
__global__ void norm_k(const int* iclus, const float* wgt, const float* allw, float* nw){
    int e = blockIdx.x * 256 + threadIdx.x;
    int b = e >> 12;
    nw[e] = wgt[e] / allw[(b << 10) + (iclus[e] & 1023)];
}
__global__ void abuf_k(const int* idx_agg, const void* aggw, const float* nw,
                       float* abuf, float* maxw, const int* mode){
    int m = GETM(mode);
    int e = blockIdx.x * 256 + threadIdx.x;
    int b = e >> 12;
    float a = ldin(aggw, e, m) * nw[(b << 12) + (idx_agg[e] & 4095)];
    abuf[e] = a;
    atomicMax((int*)&maxw[b], __float_as_int(a));
}
__global__ __launch_bounds__(128) void scatter_xdown(const int* iclus, const float* nw,
                                                     const float* xtok, float* xdown){
    int bn = blockIdx.x;           // 0..16383
    int b = bn >> 12;
    int cl = iclus[bn] & 1023;
    float w = nw[bn];
    const float* src = xtok + (size_t)bn * 512;
    float* dst = xdown + ((size_t)(b << 10) + cl) * 512;
    int c = threadIdx.x * 4;
    float4 v = *(const float4*)&src[c];
    unsafeAtomicAdd(&dst[c + 0], v.x * w);
    unsafeAtomicAdd(&dst[c + 1], v.y * w);
    unsafeAtomicAdd(&dst[c + 2], v.z * w);
    unsafeAtomicAdd(&dst[c + 3], v.w * w);
}

__global__ void out0_k(const float* xdown, float* out){
    int e = blockIdx.x * 256 + threadIdx.x;
    if(e < 2097152) out[e] = xdown[e];
}
// fused out1 + out2 (both 16384-elem)
__global__ void out12_k(const int* idx_agg, const int* iclus, const float* abuf,
                        const float* maxw, float* out){
    int e = blockIdx.x * 256 + threadIdx.x;   // 16384
    int b = e >> 12;
    int ic = iclus[(b << 12) + (idx_agg[e] & 4095)];
    out[2097152 + e] = (float)ic;
    out[2097152 + 16384 + e] = abuf[e] / maxw[b];
}

// ---------- launch ----------
extern "C" void kernel_launch(void* const* d_in, const int* in_sizes, int n_in,
                              void* d_out, int out_size, void* d_ws, size_t ws_size,
                              hipStream_t stream){
    (void)in_sizes; (void)n_in; (void)out_size; (void)ws_size;
    const void* x    = d_in[0];
    const void* loc  = d_in[1];
    const int* idx_agg = (const int*)d_in[2];
    const void* aggw = d_in[3];
    const void* cw   = d_in[7];
    const void* cb   = d_in[8];
    const void* sw   = d_in[9];
    const void* lg   = d_in[10];
    const void* lnb  = d_in[11];
    const void* cfw  = d_in[12];
    const void* cfb  = d_in[13];
    float* out = (float*)d_out;

    // Flat layout: 20,848,649 floats = 83.4 MB (unchanged footprint).
    // SP (fp16 split arrays, 32 MB) exactly aliases xmap+convo+xdown, which are dead
    // during the clustering phase (xdown memset moved after gramC3).
    float* ws    = (float*)d_ws;
    float* xtok  = ws;                        // 8,388,608
    float* xmap  = ws + 8388608;              // 4,194,304  (SP region start)
    float* convo = ws + 12582912;             // 2,097,152  (SP cont.)
    float* xdown = ws + 14680064;             // 2,097,152  (SP cont.)
    unsigned short* SP = (unsigned short*)(ws + 8388608);   // 2*64*16384*8 u16 = 32 MB
    float* cnt   = ws + 16777216;             // 16,384
    float* part5 = ws + 16793600;             // 2,621,440
    float* pmaxb = ws + 19415040;             // 524,288
    float* pminb = ws + 19939328;             // 524,288
    float* pcd   = ws + 20463616;             // 131,072
    int*   pci   = (int*)(ws + 20594688);     // 131,072
    float* x2    = ws + 20725760;             // 16,384
    float* wgt   = ws + 20742144;             // 16,384
    float* dens  = ws + 20758528;             // 16,384
    float* score = ws + 20774912;             // 16,384
    float* wsum  = ws + 20791296;             // 16,384
    float* allw  = ws + 20807680;             // 4,096 (adjacent to wsum)
    float* nw    = ws + 20811776;             // 16,384
    float* dmaxf = ws + 20828160;             // 4
    float* maxw  = ws + 20828164;             // 4
    int*   idown = (int*)(ws + 20828168);     // 4,096
    int*   iclus = (int*)(ws + 20832264);     // 16,384
    int*   mode  = (int*)(ws + 20848648);     // 1 (hit count)

    hipMemsetAsync(mode, 0, 4, stream);
    detect_mode<<<64, 256, 0, stream>>>(x, mode);

    hipMemsetAsync(xmap, 0, (size_t)4194304 * 4, stream);
    hipMemsetAsync(cnt, 0, (size_t)16384 * 4, stream);
    hipMemsetAsync(dmaxf, 0, 8 * 4, stream);                         // dmax[4] + maxw[4]
    fill_f32<<<80, 256, 0, stream>>>(wsum, 1e-6f, 20480);            // wsum + allw (adjacent)

    scatter_map<<<16384, 256, 0, stream>>>(x, loc, idx_agg, xmap, cnt, mode);
    divide_map<<<16384, 256, 0, stream>>>(xmap, cnt, 4194304);

    init_convo<<<8192, 256, 0, stream>>>(convo, cb, mode);
    gemm_conv<<<dim3(4, 32, 4), 256, 0, stream>>>(xmap, cw, convo, mode);
    gemm_skip<<<dim3(8, 256), 256, 0, stream>>>(x, sw, xtok, mode);

    wsum_add<<<64, 256, 0, stream>>>(idx_agg, aggw, wsum, mode);
    scatter_tok<<<16384, 128, 0, stream>>>(loc, idx_agg, aggw, convo, wsum, xtok, mode);
    ln_conf<<<16384, 128, 0, stream>>>(xtok, lg, lnb, cfw, cfb, wgt, x2, mode);

    // ---- clustering: fp16-split MFMA Gram passes ----
    split2<<<4096, 256, 0, stream>>>(xtok, SP);
    gramA3<<<dim3(528, 1, 4), 256, 0, stream>>>(SP, x2, part5, pmaxb);
    reduceA2<<<16384, 64, 0, stream>>>(part5, pmaxb, dens, (int*)dmaxf);
    gramB3<<<dim3(528, 1, 4), 256, 0, stream>>>(SP, x2, dens, pminb);
    reduceB2<<<16384, 64, 0, stream>>>(pminb, dens, (int*)dmaxf, score);
    sort_topk<<<4, 1024, 0, stream>>>(score, idown);
    gramC3<<<dim3(32, 8, 4), 256, 0, stream>>>(SP, x2, idown, pcd, pci);
    reduceC2<<<64, 256, 0, stream>>>(pcd, pci, iclus);

    hipMemsetAsync(xdown, 0, (size_t)2097152 * 4, stream);           // SP dead now

    allw_add<<<64, 256, 0, stream>>>(iclus, wgt, allw);
    norm_k<<<64, 256, 0, stream>>>(iclus, wgt, allw, nw);
    abuf_k<<<64, 256, 0, stream>>>(idx_agg, aggw, nw, score, maxw, mode);   // score reused as abuf

    scatter_xdown<<<16384, 128, 0, stream>>>(iclus, nw, xtok, xdown);

    out0_k<<<8192, 256, 0, stream>>>(xdown, out);
    out12_k<<<64, 256, 0, stream>>>(idx_agg, iclus, score, maxw, out);
}

// Round 2
// 1434.271 us; speedup vs baseline: 1.6289x; 1.2037x over previous
//
#include <hip/hip_runtime.h>

#define FLTMAX 3.402823466e+38f

// ---------- helpers ----------
__device__ inline float b2f(unsigned short u){
    return __uint_as_float(((unsigned int)u) << 16);
}
// flag-dispatched input load: mode=1 -> f32 buffer, mode=0 -> bf16 buffer
__device__ inline float ldin(const void* p, long i, int f32m){
    return f32m ? ((const float*)p)[i] : b2f(((const unsigned short*)p)[i]);
}
__device__ inline int pix_idx(float lx, float ly, float half_, int wh){
    lx = fminf(fmaxf(lx, -1.f), 1.f);
    ly = fminf(fmaxf(ly, -1.f), 1.f);
    int px = (int)rintf((lx + 1.f) * half_ - 0.5f);   // round-half-even = jnp.round
    int py = (int)rintf((ly + 1.f) * half_ - 0.5f);
    px = min(max(px, 0), wh - 1);
    py = min(max(py, 0), wh - 1);
    return py * wh + px;
}
__device__ inline void ins5(float* b5, float d){
    if(d < b5[4]){
        b5[4] = d;
#pragma unroll
        for(int q = 4; q > 0; --q){
            if(b5[q] < b5[q-1]){ float tm = b5[q]; b5[q] = b5[q-1]; b5[q-1] = tm; }
        }
    }
}
__device__ inline float wred_add(float v){
    for(int o = 32; o > 0; o >>= 1) v += __shfl_down(v, o);
    return v;
}

// ---------- dtype auto-detect (64 blocks, atomic count; mode[0] = hit count) ----------
__global__ __launch_bounds__(256) void detect_mode(const void* xraw, int* flag){
    __shared__ int sh[256];
    const unsigned short* p = (const unsigned short*)xraw;
    int t = threadIdx.x, c = 0;
    int base = blockIdx.x * 1024;
    for(int i = base + t; i < base + 1024; i += 256){
        float v = b2f(p[i]);
        if(!(fabsf(v) < 100.f)) c++;
    }
    sh[t] = c;
    __syncthreads();
    for(int s = 128; s > 0; s >>= 1){
        if(t < s) sh[t] += sh[t + s];
        __syncthreads();
    }
    if(t == 0 && sh[0] > 0) atomicAdd(flag, sh[0]);
}
#define GETM(modeptr) (((*(modeptr)) > 64) ? 1 : 0)

// ---------- small utility kernels ----------
__global__ void fill_f32(float* p, float v, int n){
    int i = blockIdx.x * blockDim.x + threadIdx.x;
    if(i < n) p[i] = v;
}

// token2map scatter
__global__ __launch_bounds__(256) void scatter_map(const void* x, const void* loc,
                                                   const int* idx_agg, float* acc, float* cnt,
                                                   const int* mode){
    int m = GETM(mode);
    int bn = blockIdx.x;                 // 0..16383
    int b = bn >> 12;
    float lx = ldin(loc, (long)bn * 2 + 0, m);
    float ly = ldin(loc, (long)bn * 2 + 1, m);
    int p = pix_idx(lx, ly, 32.f, 64);
    int ia = idx_agg[bn] & 4095;
    long src = ((long)(b << 12) + ia) * 256;
    float* dst = acc + ((size_t)(b << 12) + p) * 256;
    int t = threadIdx.x;                 // 256 = C
    unsafeAtomicAdd(&dst[t], ldin(x, src + t, m));
    if(t == 0) unsafeAtomicAdd(&cnt[(b << 12) + p], 1.0f);
}

__global__ void divide_map(float* xmap, const float* cnt, int n){
    int i = blockIdx.x * 256 + threadIdx.x;
    if(i < n) xmap[i] = xmap[i] / (cnt[i >> 8] + 1e-6f);
}

// ---------- conv C init with bias ----------
__global__ void init_convo(float* convo, const void* bias, const int* mode){
    int m = GETM(mode);
    int e = blockIdx.x * 256 + threadIdx.x;   // 2,097,152
    convo[e] = ldin(bias, e & 511, m);
}

// ================== MFMA infra (fp16 2-way split, 3-product exact emulation) ==================
typedef _Float16 half8 __attribute__((ext_vector_type(8)));
typedef float f32x16 __attribute__((ext_vector_type(16)));
#define MFMA16(A,B,C) __builtin_amdgcn_mfma_f32_32x32x16_f16(A,B,C,0,0,0)

__device__ inline void gld16(const unsigned short* g, unsigned short* l){
    __builtin_amdgcn_global_load_lds((const __attribute__((address_space(1))) unsigned int*)g,
                                     (__attribute__((address_space(3))) unsigned int*)l, 16, 0, 0);
}
__device__ inline void split2w(const float* v, unsigned* hw, unsigned* lw){
#pragma unroll
    for(int u = 0; u < 4; ++u){
        _Float16 h0 = (_Float16)v[2*u];
        _Float16 l0 = (_Float16)(v[2*u] - (float)h0);
        _Float16 h1 = (_Float16)v[2*u+1];
        _Float16 l1 = (_Float16)(v[2*u+1] - (float)h1);
        hw[u] = (((unsigned)__builtin_bit_cast(unsigned short, h1)) << 16) | __builtin_bit_cast(unsigned short, h0);
        lw[u] = (((unsigned)__builtin_bit_cast(unsigned short, l1)) << 16) | __builtin_bit_cast(unsigned short, l0);
    }
}

// split kernel: xtok f32 [16384][512] -> SP[2][64][16384][8] fp16 bits
__global__ __launch_bounds__(256) void split2(const float* xt, unsigned short* SP){
    int e = blockIdx.x * 256 + threadIdx.x;   // 1,048,576 = 64 groups * 16384 rows
    int g = e >> 14, row = e & 16383;
    const float* src = xt + (size_t)row * 512 + g * 8;
    float4 a = *(const float4*)src;
    float4 b = *(const float4*)(src + 4);
    float v[8] = {a.x, a.y, a.z, a.w, b.x, b.y, b.z, b.w};
    unsigned hw[4], lw[4];
    split2w(v, hw, lw);
    *(uint4*)(void*)(SP + ((size_t)g * 16384 + row) * 8) = make_uint4(hw[0], hw[1], hw[2], hw[3]);
    *(uint4*)(void*)(SP + ((size_t)(64 + g) * 16384 + row) * 8) = make_uint4(lw[0], lw[1], lw[2], lw[3]);
}

// xmap f32 [4][64][64][256] -> XMS[2][32][4*66*66][8] f16 (zero-padded 66x66 grid)
__global__ __launch_bounds__(256) void split_xmap(const float* xmap, unsigned short* XMS){
    int e = blockIdx.x * 256 + threadIdx.x;      // 557,568 = 17424*32
    int g = e & 31, pix = e >> 5;
    int b = pix / 4356, r = pix - b * 4356;
    int py = r / 66, px = r - py * 66;
    float v[8];
    if(py >= 1 && py <= 64 && px >= 1 && px <= 64){
        const float* src = xmap + ((size_t)(b << 12) + ((py - 1) << 6) + (px - 1)) * 256 + g * 8;
        float4 a = *(const float4*)src;
        float4 c = *(const float4*)(src + 4);
        v[0]=a.x; v[1]=a.y; v[2]=a.z; v[3]=a.w; v[4]=c.x; v[5]=c.y; v[6]=c.z; v[7]=c.w;
    } else {
#pragma unroll
        for(int u = 0; u < 8; ++u) v[u] = 0.f;
    }
    unsigned hw[4], lw[4];
    split2w(v, hw, lw);
    *(uint4*)(void*)(XMS + ((size_t)g * 17424 + pix) * 8) = make_uint4(hw[0], hw[1], hw[2], hw[3]);
    *(uint4*)(void*)(XMS + ((size_t)(32 + g) * 17424 + pix) * 8) = make_uint4(lw[0], lw[1], lw[2], lw[3]);
}

// conv_w [2304][512] -> CWT[2][288][512][8] (k-transposed: row j holds its k-vector)
__global__ __launch_bounds__(256) void split_cw(const void* cwp, unsigned short* CWT, const int* mode){
    int m = GETM(mode);
    int e = blockIdx.x * 256 + threadIdx.x;   // 147,456 = 288*512
    int col = e & 511, kg = e >> 9;
    float v[8];
#pragma unroll
    for(int u = 0; u < 8; ++u) v[u] = ldin(cwp, (long)(kg * 8 + u) * 512 + col, m);
    unsigned hw[4], lw[4];
    split2w(v, hw, lw);
    *(uint4*)(void*)(CWT + ((size_t)kg * 512 + col) * 8) = make_uint4(hw[0], hw[1], hw[2], hw[3]);
    *(uint4*)(void*)(CWT + ((size_t)(288 + kg) * 512 + col) * 8) = make_uint4(lw[0], lw[1], lw[2], lw[3]);
}

// skip_w [256][512] -> SWT[2][32][512][8]
__global__ __launch_bounds__(256) void split_sw(const void* swp, unsigned short* SWT, const int* mode){
    int m = GETM(mode);
    int e = blockIdx.x * 256 + threadIdx.x;   // 16,384 = 32*512
    int col = e & 511, kg = e >> 9;
    float v[8];
#pragma unroll
    for(int u = 0; u < 8; ++u) v[u] = ldin(swp, (long)(kg * 8 + u) * 512 + col, m);
    unsigned hw[4], lw[4];
    split2w(v, hw, lw);
    *(uint4*)(void*)(SWT + ((size_t)kg * 512 + col) * 8) = make_uint4(hw[0], hw[1], hw[2], hw[3]);
    *(uint4*)(void*)(SWT + ((size_t)(32 + kg) * 512 + col) * 8) = make_uint4(lw[0], lw[1], lw[2], lw[3]);
}

// x (mode-typed) [16384][256] -> XS[2][32][16384][8]
__global__ __launch_bounds__(256) void split_x(const void* xp, unsigned short* XS, const int* mode){
    int m = GETM(mode);
    int e = blockIdx.x * 256 + threadIdx.x;   // 524,288 = 32*16384
    int g = e & 31, row = e >> 5;
    long base = (long)row * 256 + g * 8;
    float v[8];
#pragma unroll
    for(int u = 0; u < 8; ++u) v[u] = ldin(xp, base + u, m);
    unsigned hw[4], lw[4];
    split2w(v, hw, lw);
    *(uint4*)(void*)(XS + ((size_t)g * 16384 + row) * 8) = make_uint4(hw[0], hw[1], hw[2], hw[3]);
    *(uint4*)(void*)(XS + ((size_t)(32 + g) * 16384 + row) * 8) = make_uint4(lw[0], lw[1], lw[2], lw[3]);
}

// shared MFMA inner step (reads 32KB staged tile: [s][tile][gl][128row][8])
#define MFMA_STEP \
    const half8* stv = (const half8*)stage; \
    _Pragma("unroll") \
    for(int ks = 0; ks < 2; ++ks){ \
        int kg = (ks << 1) + kh; \
        half8 ah0 = stv[kg*128 + rb];        half8 ah1 = stv[kg*128 + rb + 32]; \
        half8 bh0 = stv[(4+kg)*128 + cbx];   half8 bh1 = stv[(4+kg)*128 + cbx + 32]; \
        half8 al0 = stv[(8+kg)*128 + rb];    half8 al1 = stv[(8+kg)*128 + rb + 32]; \
        half8 bl0 = stv[(12+kg)*128 + cbx];  half8 bl1 = stv[(12+kg)*128 + cbx + 32]; \
        acc00 = MFMA16(ah0,bh0,acc00); acc00 = MFMA16(ah0,bl0,acc00); acc00 = MFMA16(al0,bh0,acc00); \
        acc01 = MFMA16(ah0,bh1,acc01); acc01 = MFMA16(ah0,bl1,acc01); acc01 = MFMA16(al0,bh1,acc01); \
        acc10 = MFMA16(ah1,bh0,acc10); acc10 = MFMA16(ah1,bl0,acc10); acc10 = MFMA16(al1,bh0,acc10); \
        acc11 = MFMA16(ah1,bh1,acc11); acc11 = MFMA16(ah1,bl1,acc11); acc11 = MFMA16(al1,bh1,acc11); \
    }

// ---------- conv3x3 s2 p1 via im2col on MFMA: 128x128 tile, K-split x4, atomic epilogue ----------
__global__ __launch_bounds__(256) void conv_mfma(const unsigned short* XMS, const unsigned short* CWT,
                                                 float* C){
    __shared__ __align__(16) unsigned short stage[16384];
    int t = threadIdx.x;
    int j0 = blockIdx.x * 128;                // 4
    int i0 = blockIdx.y * 128;                // 32
    int kz = blockIdx.z;                      // 4 (K chunks of 576)
    int w = t >> 6, lane = t & 63, kh = lane >> 5;
    int row = t & 127, glo = t >> 7;
    int p = i0 + row;
    int b = p >> 10, r = p & 1023, oy = r >> 5, ox = r & 31;
    long pixbase = (long)b * 4356 + oy * 132 + ox * 2;
    long colv = (long)(j0 + row) * 8;
    f32x16 acc00, acc01, acc10, acc11;
#pragma unroll
    for(int q = 0; q < 16; ++q){ acc00[q]=0.f; acc01[q]=0.f; acc10[q]=0.f; acc11[q]=0.f; }
    unsigned short* ldsb = stage + (size_t)(t & 192) * 8;
    int rb = ((w >> 1) << 6) + (lane & 31);
    int cbx = ((w & 1) << 6) + (lane & 31);
    for(int c_ = 0; c_ < 18; ++c_){
        int cg = kz * 18 + c_;
        int tap = cg >> 3;                    // 0..8 (chunk of 32 stays within one tap)
        int tdiv = tap / 3;
        long toff = (long)tdiv * 66 + (tap - tdiv * 3);
        int c8 = (cg & 7) << 2;               // channel kgroup base
        long apix = (pixbase + toff) * 8;
        const unsigned short* a0 = XMS + (size_t)(c8 + glo)          * 139392 + apix;
        const unsigned short* a1 = XMS + (size_t)(c8 + 2 + glo)      * 139392 + apix;
        const unsigned short* a4 = XMS + (size_t)(32 + c8 + glo)     * 139392 + apix;
        const unsigned short* a5 = XMS + (size_t)(32 + c8 + 2 + glo) * 139392 + apix;
        const unsigned short* b2 = CWT + (size_t)((cg << 2) + glo)           * 4096 + colv;
        const unsigned short* b3 = CWT + (size_t)((cg << 2) + 2 + glo)       * 4096 + colv;
        const unsigned short* b6 = CWT + (size_t)(288 + (cg << 2) + glo)     * 4096 + colv;
        const unsigned short* b7 = CWT + (size_t)(288 + (cg << 2) + 2 + glo) * 4096 + colv;
        __syncthreads();
        gld16(a0, ldsb);          gld16(a1, ldsb + 2048);
        gld16(b2, ldsb + 4096);   gld16(b3, ldsb + 6144);
        gld16(a4, ldsb + 8192);   gld16(a5, ldsb + 10240);
        gld16(b6, ldsb + 12288);  gld16(b7, ldsb + 14336);
        __syncthreads();
        MFMA_STEP
    }
    int rbase = i0 + ((w >> 1) << 6);
    int cbase = j0 + ((w & 1) << 6) + (lane & 31);
#pragma unroll
    for(int q = 0; q < 16; ++q){
        int rL = (q & 3) + ((q >> 2) << 3) + (kh << 2);
        unsafeAtomicAdd(&C[(size_t)(rbase + rL) * 512 + cbase],           acc00[q]);
        unsafeAtomicAdd(&C[(size_t)(rbase + rL) * 512 + cbase + 32],      acc01[q]);
        unsafeAtomicAdd(&C[(size_t)(rbase + 32 + rL) * 512 + cbase],      acc10[q]);
        unsafeAtomicAdd(&C[(size_t)(rbase + 32 + rL) * 512 + cbase + 32], acc11[q]);
    }
}

// ---------- skip GEMM on MFMA: x[16384,256] @ skip_w -> xtok (direct store) ----------
__global__ __launch_bounds__(256) void skip_mfma(const unsigned short* XS, const unsigned short* SWT,
                                                 float* C){
    __shared__ __align__(16) unsigned short stage[16384];
    int t = threadIdx.x;
    int j0 = blockIdx.x * 128;                // 4
    int i0 = blockIdx.y * 128;                // 128
    int w = t >> 6, lane = t & 63, kh = lane >> 5;
    int row = t & 127, glo = t >> 7;
    long arow = (long)(i0 + row) * 8;
    long colv = (long)(j0 + row) * 8;
    f32x16 acc00, acc01, acc10, acc11;
#pragma unroll
    for(int q = 0; q < 16; ++q){ acc00[q]=0.f; acc01[q]=0.f; acc10[q]=0.f; acc11[q]=0.f; }
    unsigned short* ldsb = stage + (size_t)(t & 192) * 8;
    int rb = ((w >> 1) << 6) + (lane & 31);
    int cbx = ((w & 1) << 6) + (lane & 31);
    for(int c_ = 0; c_ < 8; ++c_){
        const unsigned short* a0 = XS + (size_t)((c_ << 2) + glo)          * 131072 + arow;
        const unsigned short* a1 = XS + (size_t)((c_ << 2) + 2 + glo)      * 131072 + arow;
        const unsigned short* a4 = XS + (size_t)(32 + (c_ << 2) + glo)     * 131072 + arow;
        const unsigned short* a5 = XS + (size_t)(32 + (c_ << 2) + 2 + glo) * 131072 + arow;
        const unsigned short* b2 = SWT + (size_t)((c_ << 2) + glo)          * 4096 + colv;
        const unsigned short* b3 = SWT + (size_t)((c_ << 2) + 2 + glo)      * 4096 + colv;
        const unsigned short* b6 = SWT + (size_t)(32 + (c_ << 2) + glo)     * 4096 + colv;
        const unsigned short* b7 = SWT + (size_t)(32 + (c_ << 2) + 2 + glo) * 4096 + colv;
        __syncthreads();
        gld16(a0, ldsb);          gld16(a1, ldsb + 2048);
        gld16(b2, ldsb + 4096);   gld16(b3, ldsb + 6144);
        gld16(a4, ldsb + 8192);   gld16(a5, ldsb + 10240);
        gld16(b6, ldsb + 12288);  gld16(b7, ldsb + 14336);
        __syncthreads();
        MFMA_STEP
    }
    int rbase = i0 + ((w >> 1) << 6);
    int cbase = j0 + ((w & 1) << 6) + (lane & 31);
#pragma unroll
    for(int q = 0; q < 16; ++q){
        int rL = (q & 3) + ((q >> 2) << 3) + (kh << 2);
        C[(size_t)(rbase + rL) * 512 + cbase]           = acc00[q];
        C[(size_t)(rbase + rL) * 512 + cbase + 32]      = acc01[q];
        C[(size_t)(rbase + 32 + rL) * 512 + cbase]      = acc10[q];
        C[(size_t)(rbase + 32 + rL) * 512 + cbase + 32] = acc11[q];
    }
}

// ---------- map2token ----------
__global__ void wsum_add(const int* idx_agg, const void* aggw, float* wsum, const int* mode){
    int m = GETM(mode);
    int e = blockIdx.x * 256 + threadIdx.x;   // 16384
    int b = e >> 12;
    unsafeAtomicAdd(&wsum[(b << 12) + (idx_agg[e] & 4095)], ldin(aggw, e, m));
}

__global__ __launch_bounds__(128) void scatter_tok(const void* loc, const int* idx_agg,
                                                   const void* aggw, const float* convo,
                                                   const float* wsum, float* xtok, const int* mode){
    int m = GETM(mode);
    int bn = blockIdx.x;
    int b = bn >> 12;
    float lx = ldin(loc, (long)bn * 2 + 0, m);
    float ly = ldin(loc, (long)bn * 2 + 1, m);
    int p = pix_idx(lx, ly, 16.f, 32);
    int tk = idx_agg[bn] & 4095;
    float w = ldin(aggw, bn, m);
    float scale = w / wsum[(b << 12) + tk];
    const float* pv = convo + ((size_t)(b << 10) + p) * 512;
    float* dst = xtok + ((size_t)(b << 12) + tk) * 512;
    int c = threadIdx.x * 4;
    float4 v = *(const float4*)&pv[c];
    unsafeAtomicAdd(&dst[c + 0], v.x * scale);
    unsafeAtomicAdd(&dst[c + 1], v.y * scale);
    unsafeAtomicAdd(&dst[c + 2], v.z * scale);
    unsafeAtomicAdd(&dst[c + 3], v.w * scale);
}

// ---------- fused layernorm + conf + weight + x2 ----------
__global__ __launch_bounds__(128) void ln_conf(float* xtok, const void* g_, const void* b_,
                                               const void* cw_, const void* cb_,
                                               float* wgt, float* x2a, const int* mode){
    int m = GETM(mode);
    int row = blockIdx.x;        // 0..16383
    int t = threadIdx.x;         // 128
    float* xr = xtok + (size_t)row * 512;
    int c0 = t * 4;
    float4 v = *(const float4*)&xr[c0];
    float xv[4] = {v.x, v.y, v.z, v.w};
    __shared__ float red[2];
    __shared__ float red2[4];
    float s = xv[0] + xv[1] + xv[2] + xv[3];
    s = wred_add(s);
    if((t & 63) == 0) red[t >> 6] = s;
    __syncthreads();
    float mean = (red[0] + red[1]) * (1.f / 512.f);
    __syncthreads();
    float xc[4];
#pragma unroll
    for(int u = 0; u < 4; ++u) xc[u] = xv[u] - mean;
    float q = xc[0]*xc[0] + xc[1]*xc[1] + xc[2]*xc[2] + xc[3]*xc[3];
    q = wred_add(q);
    if((t & 63) == 0) red[t >> 6] = q;
    __syncthreads();
    float var = (red[0] + red[1]) * (1.f / 512.f);
    float rs = 1.0f / sqrtf(var + 1e-5f);
    float y[4];
#pragma unroll
    for(int u = 0; u < 4; ++u)
        y[u] = xc[u] * rs * ldin(g_, c0 + u, m) + ldin(b_, c0 + u, m);
    float4 st; st.x = y[0]; st.y = y[1]; st.z = y[2]; st.w = y[3];
    *(float4*)&xr[c0] = st;
    float cf = y[0]*ldin(cw_, c0+0, m) + y[1]*ldin(cw_, c0+1, m)
             + y[2]*ldin(cw_, c0+2, m) + y[3]*ldin(cw_, c0+3, m);
    float qq = y[0]*y[0] + y[1]*y[1] + y[2]*y[2] + y[3]*y[3];
    cf = wred_add(cf);
    qq = wred_add(qq);
    if((t & 63) == 0){ red2[t >> 6] = cf; red2[2 + (t >> 6)] = qq; }
    __syncthreads();
    if(t == 0){
        wgt[row] = expf(red2[0] + red2[1] + ldin(cb_, 0, m));
        x2a[row] = red2[2] + red2[3];
    }
}

// per-thread staging pointer init for the Gram; cell = [s][tile][gl][row]
#define INITP(R, AEXPR) const unsigned short* p##R; { \
    int cell = t + ((R) << 8); int row = cell & 127; int gl = (cell >> 7) & 3; \
    int tile = (cell >> 9) & 1; int sp_ = cell >> 10; \
    int grow = (z << 12) + (tile ? (j0 + row) : (AEXPR)); \
    p##R = SP + (size_t)((sp_ << 6) + gl) * 131072 + (size_t)grow * 8; }

// 128x128 Gram tile over K=512: acc{00,01,10,11} = f32x16 per wave-quadrant (2x2 of 32x32)
#define GRAM_CORE(AEXPR) \
    int w = t >> 6; int lane = t & 63; int kh = lane >> 5; \
    f32x16 acc00, acc01, acc10, acc11; \
    _Pragma("unroll") for(int q_ = 0; q_ < 16; ++q_){ acc00[q_]=0.f; acc01[q_]=0.f; acc10[q_]=0.f; acc11[q_]=0.f; } \
    INITP(0, AEXPR) INITP(1, AEXPR) INITP(2, AEXPR) INITP(3, AEXPR) \
    INITP(4, AEXPR) INITP(5, AEXPR) INITP(6, AEXPR) INITP(7, AEXPR) \
    { \
        unsigned short* ldsb = stage + (size_t)(t & 192) * 8; \
        int rb = ((w >> 1) << 6) + (lane & 31); \
        int cbx = ((w & 1) << 6) + (lane & 31); \
        for(int c_ = 0; c_ < 16; ++c_){ \
            __syncthreads(); \
            gld16(p0, ldsb);         gld16(p1, ldsb + 2048); \
            gld16(p2, ldsb + 4096);  gld16(p3, ldsb + 6144); \
            gld16(p4, ldsb + 8192);  gld16(p5, ldsb + 10240); \
            gld16(p6, ldsb + 12288); gld16(p7, ldsb + 14336); \
            p0 += 524288; p1 += 524288; p2 += 524288; p3 += 524288; \
            p4 += 524288; p5 += 524288; p6 += 524288; p7 += 524288; \
            __syncthreads(); \
            MFMA_STEP \
        } \
    }

// dump one 32x32 acc quadrant as d2 into the LDS half-tile (rows of wave's half, 64x128 f32)
#define DUMP_ONE(ACC, M, N) { \
    int coln = ((w & 1) << 6) + ((N) << 5) + (lane & 31); \
    float xc2v = x2c[coln]; \
    _Pragma("unroll") for(int q = 0; q < 16; ++q){ \
        int rL = ((M) << 5) + (q & 3) + ((q >> 2) << 3) + (kh << 2); \
        d2t[rL * 128 + coln] = x2r[(ph << 6) + rL] + xc2v - 2.0f * ACC[q]; } }

#define DUMP4 if((w >> 1) == ph){ DUMP_ONE(acc00,0,0) DUMP_ONE(acc01,0,1) DUMP_ONE(acc10,1,0) DUMP_ONE(acc11,1,1) }

// triangular block map: q -> (bi <= bj)
#define TRI_MAP(q, bi, bj)                                         \
    int bj = (int)((sqrtf(8.0f * (q) + 1.0f) - 1.0f) * 0.5f);      \
    while((bj + 1) * (bj + 2) / 2 <= (q)) bj++;                    \
    while(bj * (bj + 1) / 2 > (q)) bj--;                           \
    int bi = (q) - bj * (bj + 1) / 2;

// ---------- Pass A: top5 + max per row/col ----------
__global__ __launch_bounds__(256, 3) void gramA3(const unsigned short* SP, const float* x2b,
                                                 float* part5, float* pmax){
    __shared__ __align__(16) unsigned short stage[16384];   // 32KB staging, aliased as d2 tile
    __shared__ float x2r[128], x2c[128];
    __shared__ float scr[1536];
    float* d2t = (float*)stage;
    int z = blockIdx.z;
    TRI_MAP((int)blockIdx.x, bi, bj)
    int i0 = bi * 128, j0 = bj * 128;
    int t = threadIdx.x;
    if(t < 128) x2r[t] = x2b[(z << 12) + i0 + t];
    else        x2c[t - 128] = x2b[(z << 12) + j0 + (t - 128)];
    GRAM_CORE(i0 + row)
    float colb5[5] = {FLTMAX, FLTMAX, FLTMAX, FLTMAX, FLTMAX};
    float colmx = -FLTMAX;
    for(int ph = 0; ph < 2; ++ph){
        __syncthreads();
        DUMP4
        __syncthreads();
        {   // row scan: 4 threads/row, 32 cols each, staggered to avoid bank conflicts
            int rr = t >> 2, ch = t & 3;
            float b5[5] = {FLTMAX, FLTMAX, FLTMAX, FLTMAX, FLTMAX};
            float mx = -FLTMAX;
#pragma unroll
            for(int c = 0; c < 32; ++c){
                int cc = (rr + (ch << 3) + c) & 31;
                float v = d2t[rr * 128 + (ch << 5) + cc];
                ins5(b5, v); mx = fmaxf(mx, v);
            }
            float* sp_ = &scr[(size_t)(rr * 4 + ch) * 6];
            sp_[0]=b5[0]; sp_[1]=b5[1]; sp_[2]=b5[2]; sp_[3]=b5[3]; sp_[4]=b5[4]; sp_[5]=mx;
        }
        __syncthreads();
        if(t < 64){
            float m5[5] = {FLTMAX, FLTMAX, FLTMAX, FLTMAX, FLTMAX};
            float mmx = -FLTMAX;
            for(int c2 = 0; c2 < 4; ++c2){
                const float* sp_ = &scr[(size_t)(t * 4 + c2) * 6];
                ins5(m5, sp_[0]); ins5(m5, sp_[1]); ins5(m5, sp_[2]); ins5(m5, sp_[3]); ins5(m5, sp_[4]);
                mmx = fmaxf(mmx, sp_[5]);
            }
            size_t rowg = (size_t)(z << 12) + i0 + (ph << 6) + t;
            size_t o = (rowg * 32 + bj) * 5;
            part5[o]=m5[0]; part5[o+1]=m5[1]; part5[o+2]=m5[2]; part5[o+3]=m5[3]; part5[o+4]=m5[4];
            pmax[rowg * 32 + bj] = mmx;
        }
        __syncthreads();
        if(bi != bj){   // col partials (2 threads/col, 32 rows each)
            int col = t >> 1, rh = t & 1;
            float c5[5] = {FLTMAX, FLTMAX, FLTMAX, FLTMAX, FLTMAX};
            float cmx = -FLTMAX;
#pragma unroll
            for(int r2 = 0; r2 < 32; ++r2){
                float v = d2t[((rh << 5) + r2) * 128 + col];
                ins5(c5, v); cmx = fmaxf(cmx, v);
            }
            float* sp_ = &scr[(size_t)(col * 2 + rh) * 6];
            sp_[0]=c5[0]; sp_[1]=c5[1]; sp_[2]=c5[2]; sp_[3]=c5[3]; sp_[4]=c5[4]; sp_[5]=cmx;
        }
        __syncthreads();
        if(bi != bj && t < 128){
            const float* sa = &scr[(size_t)(t * 2) * 6];
            ins5(colb5, sa[0]); ins5(colb5, sa[1]); ins5(colb5, sa[2]); ins5(colb5, sa[3]); ins5(colb5, sa[4]);
            colmx = fmaxf(colmx, sa[5]);
            const float* sb = &scr[(size_t)(t * 2 + 1) * 6];
            ins5(colb5, sb[0]); ins5(colb5, sb[1]); ins5(colb5, sb[2]); ins5(colb5, sb[3]); ins5(colb5, sb[4]);
            colmx = fmaxf(colmx, sb[5]);
        }
    }
    if(bi != bj && t < 128){
        size_t rowg = (size_t)(z << 12) + j0 + t;
        size_t o = (rowg * 32 + bi) * 5;
        part5[o]=colb5[0]; part5[o+1]=colb5[1]; part5[o+2]=colb5[2]; part5[o+3]=colb5[3]; part5[o+4]=colb5[4];
        pmax[rowg * 32 + bi] = colmx;
    }
}

__global__ __launch_bounds__(64) void reduceA2(const float* part5, const float* pmax,
                                               float* dens_b, int* dmax_b){
    int bi = blockIdx.x, t = threadIdx.x;     // bi = z*4096 + i, 0..16383
    __shared__ float l5[32][5];
    __shared__ float lm[32];
    if(t < 32){
#pragma unroll
        for(int q = 0; q < 5; ++q) l5[t][q] = part5[((size_t)bi * 32 + t) * 5 + q];
        lm[t] = pmax[(size_t)bi * 32 + t];
    }
    __syncthreads();
    if(t == 0){
        float m5[5] = {FLTMAX, FLTMAX, FLTMAX, FLTMAX, FLTMAX};
        float mm = -FLTMAX;
        for(int c = 0; c < 32; ++c){
            mm = fmaxf(mm, lm[c]);
#pragma unroll
            for(int q = 0; q < 5; ++q) ins5(m5, l5[c][q]);
        }
        const float sqrtC = 22.627416997969522f;
        float s = 0.f;
#pragma unroll
        for(int q = 0; q < 5; ++q){
            float d = sqrtf(fmaxf(m5[q], 0.f)) / sqrtC;
            s = s + d * d;
        }
        dens_b[bi] = expf(-(s / 5.0f));
        atomicMax(dmax_b + (bi >> 12), __float_as_int(fmaxf(mm, 0.f)));
    }
}

// ---------- Pass B: min dist to any higher-density token ----------
__global__ __launch_bounds__(256, 3) void gramB3(const unsigned short* SP, const float* x2b,
                                                 const float* dens_b, float* pmin){
    __shared__ __align__(16) unsigned short stage[16384];
    __shared__ float x2r[128], x2c[128], densr[128], densc[128];
    __shared__ float scr[256];
    float* d2t = (float*)stage;
    int z = blockIdx.z;
    TRI_MAP((int)blockIdx.x, bi, bj)
    int i0 = bi * 128, j0 = bj * 128;
    int t = threadIdx.x;
    if(t < 128){ x2r[t] = x2b[(z << 12) + i0 + t]; densr[t] = dens_b[(z << 12) + i0 + t]; }
    else { x2c[t-128] = x2b[(z << 12) + j0 + (t-128)]; densc[t-128] = dens_b[(z << 12) + j0 + (t-128)]; }
    GRAM_CORE(i0 + row)
    float colmin = FLTMAX;
    for(int ph = 0; ph < 2; ++ph){
        __syncthreads();
        DUMP4
        __syncthreads();
        {
            int rr = t >> 2, ch = t & 3;
            float dr = densr[(ph << 6) + rr];
            float pm = FLTMAX;
#pragma unroll
            for(int c = 0; c < 32; ++c){
                int cc = (rr + (ch << 3) + c) & 31;
                int coln = (ch << 5) + cc;
                float v = d2t[rr * 128 + coln];
                if(densc[coln] > dr) pm = fminf(pm, v);
            }
            scr[rr * 4 + ch] = pm;
        }
        __syncthreads();
        if(t < 64){
            float pm = fminf(fminf(scr[t*4], scr[t*4+1]), fminf(scr[t*4+2], scr[t*4+3]));
            pmin[((size_t)(z << 12) + i0 + (ph << 6) + t) * 32 + bj] = pm;
        }
        __syncthreads();
        if(bi != bj){
            int col = t >> 1, rh = t & 1;
            float dc = densc[col];
            float pm = FLTMAX;
#pragma unroll
            for(int r2 = 0; r2 < 32; ++r2){
                int rL = (rh << 5) + r2;
                float v = d2t[rL * 128 + col];
                if(densr[(ph << 6) + rL] > dc) pm = fminf(pm, v);
            }
            scr[col * 2 + rh] = pm;
        }
        __syncthreads();
        if(bi != bj && t < 128) colmin = fminf(colmin, fminf(scr[t*2], scr[t*2+1]));
    }
    if(bi != bj && t < 128) pmin[((size_t)(z << 12) + j0 + t) * 32 + bi] = colmin;
}

__global__ __launch_bounds__(64) void reduceB2(const float* pmin, const float* dens_b,
                                               const int* dmax_b, float* score_b){
    int bi = blockIdx.x, t = threadIdx.x;     // 0..16383
    __shared__ float lm[32];
    if(t < 32) lm[t] = pmin[(size_t)bi * 32 + t];
    __syncthreads();
    if(t == 0){
        float m = FLTMAX;
        for(int c = 0; c < 32; ++c) m = fminf(m, lm[c]);
        const float sqrtC = 22.627416997969522f;
        float dp;
        if(m == FLTMAX) dp = sqrtf(fmaxf(__int_as_float(dmax_b[bi >> 12]), 0.f)) / sqrtC;
        else            dp = sqrtf(fmaxf(m, 0.f)) / sqrtC;
        score_b[bi] = dp * dens_b[bi];
    }
}

// ---------- Pass C: gathered-center Gram -> per-(token, centerblock) argmin ----------
__global__ __launch_bounds__(256, 3) void gramC3(const unsigned short* SP, const float* x2b,
                                                 const int* idown_b, float* pcd, int* pci){
    __shared__ __align__(16) unsigned short stage[16384];
    __shared__ float x2r[128], x2c[128];
    __shared__ int idzl[128];
    __shared__ float scrD[256];
    __shared__ int scrI[256];
    float* d2t = (float*)stage;
    int z = blockIdx.z;
    int s0 = blockIdx.y * 128, j0 = blockIdx.x * 128;
    int t = threadIdx.x;
    if(t < 128) idzl[t] = idown_b[(z << 10) + s0 + t];
    else        x2c[t - 128] = x2b[(z << 12) + j0 + (t - 128)];
    __syncthreads();
    if(t < 128) x2r[t] = x2b[(z << 12) + idzl[t]];
    GRAM_CORE(idzl[row])
    const float sqrtC = 22.627416997969522f;
    float bd = FLTMAX; int bs = 0;
    for(int ph = 0; ph < 2; ++ph){
        __syncthreads();
        DUMP4
        __syncthreads();
        {
            int col = t >> 1, rh = t & 1;
            float ld = FLTMAX; int li = 0;
#pragma unroll
            for(int r2 = 0; r2 < 32; ++r2){      // ascending row => first-min ties stay first
                int rL = (rh << 5) + r2;
                float d2v = d2t[rL * 128 + col];
                float d = sqrtf(fmaxf(d2v, 0.f)) / sqrtC;
                if(d < ld){ ld = d; li = (ph << 6) + rL; }
            }
            scrD[col * 2 + rh] = ld; scrI[col * 2 + rh] = li;
        }
        __syncthreads();
        if(t < 128){
            if(scrD[t*2]   < bd){ bd = scrD[t*2];   bs = scrI[t*2]; }
            if(scrD[t*2+1] < bd){ bd = scrD[t*2+1]; bs = scrI[t*2+1]; }
        }
    }
    if(t < 128){
        pcd[((size_t)(z << 12) + j0 + t) * 8 + blockIdx.y] = bd;
        pci[((size_t)(z << 12) + j0 + t) * 8 + blockIdx.y] = s0 + bs;
    }
}

__global__ void reduceC2(const float* pcd, const int* pci, int* iclus_b){
    int jg = blockIdx.x * 256 + threadIdx.x;      // 0..16383
    float bd = FLTMAX;
    int bs = 0;
    for(int c = 0; c < 8; ++c){
        float d = pcd[(size_t)jg * 8 + c];
        if(d < bd){ bd = d; bs = pci[(size_t)jg * 8 + c]; }
    }
    iclus_b[jg] = bs;
}

// ---------- bitonic sort (score desc, idx asc) -> top 1024; blockIdx.x = batch ----------
__global__ __launch_bounds__(1024) void sort_topk(const float* score, int* idown){
    __shared__ float ss[4096];
    __shared__ int sid[4096];
    int t = threadIdx.x;
    const float* sc = score + (size_t)blockIdx.x * 4096;
    int* id = idown + (size_t)blockIdx.x * 1024;
    for(int v = t; v < 4096; v += 1024){ ss[v] = sc[v]; sid[v] = v; }
    __syncthreads();
    for(int k = 2; k <= 4096; k <<= 1){
        for(int j = k >> 1; j > 0; j >>= 1){
            for(int v = t; v < 4096; v += 1024){
                int l = v ^ j;
                if(l > v){
                    float sv = ss[v], sl = ss[l];
                    int iv = sid[v], il = sid[l];
                    bool before_lv = (sl > sv) || (sl == sv && il < iv);
                    bool before_vl = (sv > sl) || (sv == sl && iv < il);
                    bool asc = ((v & k) == 0);
                    bool sw = asc ? before_lv : before_vl;
                    if(sw){ ss[v] = sl; ss[l] = sv; sid[v] = il; sid[l] = iv; }
                }
            }
            __syncthreads();
        }
    }
    for(int v = t; v < 1024; v += 1024) id[v] = sid[v];
}

// ---------- merge tokens + outputs (FLOAT32 out) ----------
__global__ void allw_add(const int* iclus, const float* wgt, float* allw){
    int e = blockIdx.x * 256 + threadIdx.x;   // 16384
    int b = e >> 12;
    unsafeAtomicAdd(&allw[(b << 10) + (iclus[e] & 1023)], wgt[e]);
}
__global__ void norm_k(const int* iclus, const float* wgt, const float* allw, float* nw){
    int e = blockIdx.x * 256 + threadIdx.x;
    int b = e >> 12;
    nw[e] = wgt[e] / allw[(b << 10) + (iclus[e] & 1023)];
}
__global__ void abuf_k(const int* idx_agg, const void* aggw, const float* nw,
                       float* abuf, float* maxw, const int* mode){
    int m = GETM(mode);
    int e = blockIdx.x * 256 + threadIdx.x;
    int b = e >> 12;
    float a = ldin(aggw, e, m) * nw[(b << 12) + (idx_agg[e] & 4095)];
    abuf[e] = a;
    atomicMax((int*)&maxw[b], __float_as_int(a));
}
__global__ __launch_bounds__(128) void scatter_xdown(const int* iclus, const float* nw,
                                                     const float* xtok, float* xdown){
    int bn = blockIdx.x;           // 0..16383
    int b = bn >> 12;
    int cl = iclus[bn] & 1023;
    float w = nw[bn];
    const float* src = xtok + (size_t)bn * 512;
    float* dst = xdown + ((size_t)(b << 10) + cl) * 512;
    int c = threadIdx.x * 4;
    float4 v = *(const float4*)&src[c];
    unsafeAtomicAdd(&dst[c + 0], v.x * w);
    unsafeAtomicAdd(&dst[c + 1], v.y * w);
    unsafeAtomicAdd(&dst[c + 2], v.z * w);
    unsafeAtomicAdd(&dst[c + 3], v.w * w);
}

__global__ void out0_k(const float* xdown, float* out){
    int e = blockIdx.x * 256 + threadIdx.x;
    if(e < 2097152) out[e] = xdown[e];
}
// fused out1 + out2 (both 16384-elem)
__global__ void out12_k(const int* idx_agg, const int* iclus, const float* abuf,
                        const float* maxw, float* out){
    int e = blockIdx.x * 256 + threadIdx.x;   // 16384
    int b = e >> 12;
    int ic = iclus[(b << 12) + (idx_agg[e] & 4095)];
    out[2097152 + e] = (float)ic;
    out[2097152 + 16384 + e] = abuf[e] / maxw[b];
}

// ---------- launch ----------
extern "C" void kernel_launch(void* const* d_in, const int* in_sizes, int n_in,
                              void* d_out, int out_size, void* d_ws, size_t ws_size,
                              hipStream_t stream){
    (void)in_sizes; (void)n_in; (void)out_size; (void)ws_size;
    const void* x    = d_in[0];
    const void* loc  = d_in[1];
    const int* idx_agg = (const int*)d_in[2];
    const void* aggw = d_in[3];
    const void* cw   = d_in[7];
    const void* cb   = d_in[8];
    const void* sw   = d_in[9];
    const void* lg   = d_in[10];
    const void* lnb  = d_in[11];
    const void* cfw  = d_in[12];
    const void* cfb  = d_in[13];
    float* out = (float*)d_out;

    // Phase-aliased layout, total 21,258,249 floats = 85.0 MB (ws >= 101 MB proven).
    // SP region [8388608,16777216) holds: xmap(ph1-2) / convo(ph3-5) / CWT+SWT(ph3-4) / xdown(ph7) / SP(ph6).
    // Overlay [16777216,21237760): cnt(ph1) -> XMS(ph2-3) -> XS(ph4) -> gram partials + small f32 bufs (ph5+).
    float* ws    = (float*)d_ws;
    float* xtok  = ws;                        // 8,388,608
    float* xmap  = ws + 8388608;              // 4,194,304
    float* convo = ws + 12582912;             // 2,097,152
    float* xdown = ws + 14680064;             // 2,097,152
    unsigned short* SP  = (unsigned short*)(ws + 8388608);    // 16,777,216 shorts
    unsigned short* CWT = (unsigned short*)(ws + 14680064);   // 2,359,296 shorts (1,179,648 f)
    unsigned short* SWT = (unsigned short*)(ws + 15859712);   // 262,144 shorts (131,072 f)
    unsigned short* XMS = (unsigned short*)(ws + 16777216);   // 8,921,088 shorts (4,460,544 f)
    unsigned short* XS  = (unsigned short*)(ws + 16777216);   // 8,388,608 shorts (4,194,304 f)
    float* cnt   = ws + 16777216;             // 16,384 (phase 1 only)
    float* part5 = ws + 16793600;             // 2,621,440
    float* pmaxb = ws + 19415040;             // 524,288
    float* pminb = ws + 19939328;             // 524,288
    float* pcd   = ws + 20463616;             // 131,072
    int*   pci   = (int*)(ws + 20594688);     // 131,072
    float* x2    = ws + 20725760;             // 16,384
    float* wgt   = ws + 20742144;             // 16,384
    float* dens  = ws + 20758528;             // 16,384
    float* score = ws + 20774912;             // 16,384
    float* wsum  = ws + 20791296;             // 16,384
    float* allw  = ws + 20807680;             // 4,096 (adjacent to wsum)
    float* nw    = ws + 20811776;             // 16,384
    float* dmaxf = ws + 21237760;             // 4
    float* maxw  = ws + 21237764;             // 4
    int*   idown = (int*)(ws + 21237768);     // 4,096
    int*   iclus = (int*)(ws + 21241864);     // 16,384
    int*   mode  = (int*)(ws + 21258248);     // 1 (hit count)

    hipMemsetAsync(mode, 0, 4, stream);
    detect_mode<<<64, 256, 0, stream>>>(x, mode);

    hipMemsetAsync(xmap, 0, (size_t)4194304 * 4, stream);
    hipMemsetAsync(cnt, 0, (size_t)16384 * 4, stream);
    hipMemsetAsync(dmaxf, 0, 8 * 4, stream);                         // dmax[4] + maxw[4]

    scatter_map<<<16384, 256, 0, stream>>>(x, loc, idx_agg, xmap, cnt, mode);
    divide_map<<<16384, 256, 0, stream>>>(xmap, cnt, 4194304);

    // conv on MFMA
    split_xmap<<<2178, 256, 0, stream>>>(xmap, XMS);
    split_cw<<<576, 256, 0, stream>>>(cw, CWT, mode);
    init_convo<<<8192, 256, 0, stream>>>(convo, cb, mode);
    conv_mfma<<<dim3(4, 32, 4), 256, 0, stream>>>(XMS, CWT, convo);

    // skip GEMM on MFMA (XS reuses XMS region -> after conv_mfma)
    split_x<<<2048, 256, 0, stream>>>(x, XS, mode);
    split_sw<<<64, 256, 0, stream>>>(sw, SWT, mode);
    skip_mfma<<<dim3(4, 128), 256, 0, stream>>>(XS, SWT, xtok);

    fill_f32<<<80, 256, 0, stream>>>(wsum, 1e-6f, 20480);            // wsum + allw (adjacent)
    wsum_add<<<64, 256, 0, stream>>>(idx_agg, aggw, wsum, mode);
    scatter_tok<<<16384, 128, 0, stream>>>(loc, idx_agg, aggw, convo, wsum, xtok, mode);
    ln_conf<<<16384, 128, 0, stream>>>(xtok, lg, lnb, cfw, cfb, wgt, x2, mode);

    // ---- clustering: fp16-split MFMA Gram passes ----
    split2<<<4096, 256, 0, stream>>>(xtok, SP);
    gramA3<<<dim3(528, 1, 4), 256, 0, stream>>>(SP, x2, part5, pmaxb);
    reduceA2<<<16384, 64, 0, stream>>>(part5, pmaxb, dens, (int*)dmaxf);
    gramB3<<<dim3(528, 1, 4), 256, 0, stream>>>(SP, x2, dens, pminb);
    reduceB2<<<16384, 64, 0, stream>>>(pminb, dens, (int*)dmaxf, score);
    sort_topk<<<4, 1024, 0, stream>>>(score, idown);
    gramC3<<<dim3(32, 8, 4), 256, 0, stream>>>(SP, x2, idown, pcd, pci);
    reduceC2<<<64, 256, 0, stream>>>(pcd, pci, iclus);

    hipMemsetAsync(xdown, 0, (size_t)2097152 * 4, stream);           // SP/CWT/SWT dead now

    allw_add<<<64, 256, 0, stream>>>(iclus, wgt, allw);
    norm_k<<<64, 256, 0, stream>>>(iclus, wgt, allw, nw);
    abuf_k<<<64, 256, 0, stream>>>(idx_agg, aggw, nw, score, maxw, mode);   // score reused as abuf

    scatter_xdown<<<16384, 128, 0, stream>>>(iclus, nw, xtok, xdown);

    out0_k<<<8192, 256, 0, stream>>>(xdown, out);
    out12_k<<<64, 256, 0, stream>>>(idx_agg, iclus, score, maxw, out);
}